// Round 1
// baseline (154.271 us; speedup 1.0000x reference)
//
#include <hip/hip_runtime.h>
#include <hip/hip_bf16.h>

#define BB 4096
#define DD 512
#define LLAB 20
#define NN 8192
#define KK 64

constexpr float kNegInf = -1.0e9f;
constexpr float kLn2 = 0.69314718055994530942f;

__device__ __forceinline__ float dot4(const float4& a, const float4& b) {
  return a.x * b.x + a.y * b.y + a.z * b.z + a.w * b.w;
}

__device__ __forceinline__ float waveReduceSum(float v) {
#pragma unroll
  for (int s = 1; s < 64; s <<= 1) v += __shfl_xor(v, s);
  return v;
}

__device__ __forceinline__ float waveReduceMax(float v) {
#pragma unroll
  for (int s = 1; s < 64; s <<= 1) v = fmaxf(v, __shfl_xor(v, s));
  return v;
}

__global__ void init_kernel(unsigned* stats) {
  if (threadIdx.x == 0) {
    stats[0] = 0x7F800000u;  // +inf bits: running min of per_ex
    stats[1] = 0u;           // accuracy count
  }
}

// One block (256 threads = 4 waves) per row b. Each wave handles 16 negatives.
__global__ __launch_bounds__(256) void row_kernel(
    const float* __restrict__ ie, const float* __restrict__ le,
    const float* __restrict__ labels, const float* __restrict__ ale,
    const float* __restrict__ al, const int* __restrict__ nin,
    const int* __restrict__ nlb, float* __restrict__ per_ex,
    unsigned* __restrict__ stats) {
  const int b = blockIdx.x;
  const int tid = threadIdx.x;
  const int lane = tid & 63;
  const int wave = tid >> 6;

  __shared__ float sims[1 + 4 * KK];  // [pos, il(64), ll(64), ii(64), li(64)]
  __shared__ float wred[8];

  // Per-lane register fragments of this row's two embeddings.
  const float4* ie4 = (const float4*)(ie + (size_t)b * DD);
  const float4* le4 = (const float4*)(le + (size_t)b * DD);
  float4 ier0 = ie4[lane], ier1 = ie4[lane + 64];
  float4 ler0 = le4[lane], ler1 = le4[lane + 64];
  float lab = (lane < LLAB) ? labels[(size_t)b * LLAB + lane] : 0.0f;

  // sim_pos (wave 0)
  if (wave == 0) {
    float p = dot4(ier0, ler0) + dot4(ier1, ler1);
    p = waveReduceSum(p);
    if (lane == 0) sims[0] = p;
  }

#pragma unroll 2
  for (int kk = 0; kk < KK / 4; ++kk) {
    const int k = wave * (KK / 4) + kk;
    const int j_lb = __builtin_amdgcn_readfirstlane(nlb[(size_t)b * KK + k]);
    const int j_in = __builtin_amdgcn_readfirstlane(nin[(size_t)b * KK + k]);

    const float4* rle = (const float4*)(ale + (size_t)j_lb * DD);
    const float4* rie = (const float4*)(ie + (size_t)j_in * DD);
    float4 vle0 = rle[lane], vle1 = rle[lane + 64];
    float4 vie0 = rie[lane], vie1 = rie[lane + 64];

    // bad-negative masks: 20-element exact row equality
    bool ein = true, elb = true;
    if (lane < LLAB) {
      ein = (labels[(size_t)j_in * LLAB + lane] == lab);
      elb = (al[(size_t)j_lb * LLAB + lane] == lab);
    }
    const float bad_in_f = (__ballot(ein) == ~0ull) ? 1.0f : 0.0f;
    const float bad_lb_f = (__ballot(elb) == ~0ull) ? 1.0f : 0.0f;

    // 4 dot partials per lane
    float a_il = dot4(vle0, ier0) + dot4(vle1, ier1);
    float a_ll = dot4(vle0, ler0) + dot4(vle1, ler1);
    float a_ii = dot4(vie0, ier0) + dot4(vie1, ier1);
    float a_li = dot4(vie0, ler0) + dot4(vie1, ler1);

    // component-split butterfly: after 2 steps each lane carries one component
    // lane&3: 0 -> il, 1 -> ii, 2 -> ll, 3 -> li
    const bool oddl = (lane & 1) != 0;
    float sx = oddl ? a_il : a_ii;  // send the half we don't keep
    float sy = oddl ? a_ll : a_li;
    float rx = __shfl_xor(sx, 1);
    float ry = __shfl_xor(sy, 1);
    float mx = (oddl ? a_ii : a_il) + rx;
    float my = (oddl ? a_li : a_ll) + ry;
    const bool hi2 = (lane & 2) != 0;
    float s1 = hi2 ? mx : my;
    float r1 = __shfl_xor(s1, 2);
    float v = (hi2 ? my : mx) + r1;
    v += __shfl_xor(v, 4);
    v += __shfl_xor(v, 8);
    v += __shfl_xor(v, 16);
    v += __shfl_xor(v, 32);

    if (lane < 4) {
      const float bad = (lane & 1) ? bad_in_f : bad_lb_f;
      const float s = v + kNegInf * bad;
      const int slot = ((lane & 1) << 1) | ((lane >> 1) & 1);  // il0 ii2 ll1 li3
      sims[1 + slot * KK + k] = s;
    }
  }
  __syncthreads();

  // logsumexp over 257 logits; acc vs the 64 il negatives
  const float v = sims[1 + tid];
  const float s0 = sims[0];
  float wmax = waveReduceMax(v);
  if (lane == 0) wred[wave] = wmax;
  __syncthreads();
  float m = fmaxf(fmaxf(wred[0], wred[1]), fmaxf(wred[2], wred[3]));
  m = fmaxf(m, s0);
  const float e = expf(v - m);
  float wsum = waveReduceSum(e);
  if (lane == 0) wred[4 + wave] = wsum;
  __syncthreads();
  if (tid == 0) {
    const float tot = wred[4] + wred[5] + wred[6] + wred[7] + expf(s0 - m);
    const float pe = m + logf(tot) - s0;
    per_ex[b] = pe;
    atomicMin(&stats[0], __float_as_uint(fmaxf(pe, 0.0f)));
    const float max_il = wred[0];  // wave 0's max over sims[1..64]
    if (s0 >= max_il) atomicAdd(&stats[1], 1u);
  }
}

__global__ __launch_bounds__(256) void finalize_kernel(
    const float* __restrict__ per_ex, const unsigned* __restrict__ stats,
    float* __restrict__ out) {
  __shared__ float wred[4];
  const int tid = threadIdx.x;
  const int lane = tid & 63;
  const int wave = tid >> 6;
  const float minpe = __uint_as_float(stats[0]);
  const bool scale_on = (minpe < kLn2);  // max(q) > 0.5
  float sum = 0.0f;
  for (int i = tid; i < BB; i += 256) {
    const float pe = per_ex[i];
    float s = 1.0f;
    if (scale_on) {
      const float q = expf(-pe);
      const float t = 2.0f * (1.0f - q);
      const float t2 = t * t;
      s = t2 * t2;
    }
    sum += pe * s;
  }
  sum = waveReduceSum(sum);
  if (lane == 0) wred[wave] = sum;
  __syncthreads();
  if (tid == 0) {
    const float tot = wred[0] + wred[1] + wred[2] + wred[3];
    out[0] = tot / (float)BB;
    out[1] = (float)stats[1] / (float)BB;
  }
}

extern "C" void kernel_launch(void* const* d_in, const int* in_sizes, int n_in,
                              void* d_out, int out_size, void* d_ws, size_t ws_size,
                              hipStream_t stream) {
  const float* ie = (const float*)d_in[0];
  const float* le = (const float*)d_in[1];
  const float* labels = (const float*)d_in[2];
  const float* ale = (const float*)d_in[3];
  const float* al = (const float*)d_in[4];
  const int* nin = (const int*)d_in[5];
  const int* nlb = (const int*)d_in[6];
  float* out = (float*)d_out;

  float* per_ex = (float*)d_ws;
  unsigned* stats = (unsigned*)((char*)d_ws + BB * sizeof(float));

  hipLaunchKernelGGL(init_kernel, dim3(1), dim3(64), 0, stream, stats);
  hipLaunchKernelGGL(row_kernel, dim3(BB), dim3(256), 0, stream,
                     ie, le, labels, ale, al, nin, nlb, per_ex, stats);
  hipLaunchKernelGGL(finalize_kernel, dim3(1), dim3(256), 0, stream,
                     per_ex, stats, out);
}

// Round 2
// 110.686 us; speedup vs baseline: 1.3938x; 1.3938x over previous
//
#include <hip/hip_runtime.h>
#include <hip/hip_bf16.h>

#define BB 4096
#define DD 512
#define LLAB 20
#define NN 8192
#define KK 64

constexpr float kNegInf = -1.0e9f;
constexpr float kLn2 = 0.69314718055994530942f;

__device__ __forceinline__ float dot4(const float4& a, const float4& b) {
  return a.x * b.x + a.y * b.y + a.z * b.z + a.w * b.w;
}

__device__ __forceinline__ float waveReduceSum(float v) {
#pragma unroll
  for (int s = 1; s < 64; s <<= 1) v += __shfl_xor(v, s);
  return v;
}

__device__ __forceinline__ float waveReduceMax(float v) {
#pragma unroll
  for (int s = 1; s < 64; s <<= 1) v = fmaxf(v, __shfl_xor(v, s));
  return v;
}

__device__ __forceinline__ float waveReduceMin(float v) {
#pragma unroll
  for (int s = 1; s < 64; s <<= 1) v = fminf(v, __shfl_xor(v, s));
  return v;
}

__device__ __forceinline__ unsigned f2bf_rne(float x) {
  unsigned u = __float_as_uint(x);
  u += 0x7fffu + ((u >> 16) & 1u);
  return u >> 16;
}

__device__ __forceinline__ void unpack8(const uint4& p, float* f) {
  f[0] = __uint_as_float(p.x << 16);
  f[1] = __uint_as_float(p.x & 0xffff0000u);
  f[2] = __uint_as_float(p.y << 16);
  f[3] = __uint_as_float(p.y & 0xffff0000u);
  f[4] = __uint_as_float(p.z << 16);
  f[5] = __uint_as_float(p.z & 0xffff0000u);
  f[6] = __uint_as_float(p.w << 16);
  f[7] = __uint_as_float(p.w & 0xffff0000u);
}

__device__ __forceinline__ float dot8(const float* f, const float4& q0, const float4& q1) {
  return f[0] * q0.x + f[1] * q0.y + f[2] * q0.z + f[3] * q0.w +
         f[4] * q1.x + f[5] * q1.y + f[6] * q1.z + f[7] * q1.w;
}

__global__ void init_kernel(unsigned* stats) {
  if (threadIdx.x == 0) {
    stats[0] = 0u;
    stats[1] = 0u;  // accuracy count
  }
}

// f32 table -> bf16 table (packed 2 per uint), 8 elements per thread.
__global__ __launch_bounds__(256) void cvt_kernel(const float* __restrict__ src,
                                                  ushort* __restrict__ dst, int n8) {
  int i = blockIdx.x * blockDim.x + threadIdx.x;
  if (i >= n8) return;
  const float4* s4 = (const float4*)src;
  float4 a = s4[2 * i], b = s4[2 * i + 1];
  uint4 o;
  o.x = f2bf_rne(a.x) | (f2bf_rne(a.y) << 16);
  o.y = f2bf_rne(a.z) | (f2bf_rne(a.w) << 16);
  o.z = f2bf_rne(b.x) | (f2bf_rne(b.y) << 16);
  o.w = f2bf_rne(b.z) | (f2bf_rne(b.w) << 16);
  ((uint4*)dst)[i] = o;
}

// bf16-gather main pass. One block (4 waves) per row; each wave owns 16 negatives.
__global__ __launch_bounds__(256) void row_bf16_kernel(
    const float* __restrict__ ie, const float* __restrict__ le,
    const float* __restrict__ labels, const ushort* __restrict__ ie_bf,
    const ushort* __restrict__ ale_bf, const float* __restrict__ al,
    const int* __restrict__ nin, const int* __restrict__ nlb,
    float* __restrict__ per_ex, unsigned* __restrict__ stats) {
  const int b = blockIdx.x;
  const int tid = threadIdx.x;
  const int lane = tid & 63;
  const int wave = tid >> 6;

  __shared__ float sims[1 + 4 * KK];
  __shared__ float wred[8];

  // Query fragments (exact f32): elements lane*8 .. lane*8+7.
  const float4* ie4 = (const float4*)(ie + (size_t)b * DD);
  const float4* le4 = (const float4*)(le + (size_t)b * DD);
  float4 qi0 = ie4[2 * lane], qi1 = ie4[2 * lane + 1];
  float4 ql0 = le4[2 * lane], ql1 = le4[2 * lane + 1];
  float lab = (lane < LLAB) ? labels[(size_t)b * LLAB + lane] : 0.0f;

  if (wave == 0) {
    float p = dot4(qi0, ql0) + dot4(qi1, ql1);
    p = waveReduceSum(p);
    if (lane == 0) sims[0] = p;
  }

  // Prefetch this wave's 16 index pairs in one coalesced shot.
  int idx = 0;
  if (lane < 16) idx = nlb[(size_t)b * KK + wave * 16 + lane];
  else if (lane < 32) idx = nin[(size_t)b * KK + wave * 16 + (lane - 16)];

#pragma unroll 4
  for (int kk = 0; kk < 16; ++kk) {
    const int k = wave * 16 + kk;
    const int j_lb = __shfl(idx, kk);
    const int j_in = __shfl(idx, 16 + kk);

    const uint4 ple = ((const uint4*)(ale_bf + (size_t)j_lb * DD))[lane];
    const uint4 pie = ((const uint4*)(ie_bf + (size_t)j_in * DD))[lane];

    bool ein = true, elb = true;
    if (lane < LLAB) {
      ein = (labels[(size_t)j_in * LLAB + lane] == lab);
      elb = (al[(size_t)j_lb * LLAB + lane] == lab);
    }
    const float bad_in_f = (__ballot(ein) == ~0ull) ? 1.0f : 0.0f;
    const float bad_lb_f = (__ballot(elb) == ~0ull) ? 1.0f : 0.0f;

    float fle[8], fie[8];
    unpack8(ple, fle);
    unpack8(pie, fie);
    float a_il = dot8(fle, qi0, qi1);
    float a_ll = dot8(fle, ql0, ql1);
    float a_ii = dot8(fie, qi0, qi1);
    float a_li = dot8(fie, ql0, ql1);

    // component-split butterfly; lane&3: 0->il, 1->ii, 2->ll, 3->li
    const bool oddl = (lane & 1) != 0;
    float sx = oddl ? a_il : a_ii;
    float sy = oddl ? a_ll : a_li;
    float rx = __shfl_xor(sx, 1);
    float ry = __shfl_xor(sy, 1);
    float mx = (oddl ? a_ii : a_il) + rx;
    float my = (oddl ? a_li : a_ll) + ry;
    const bool hi2 = (lane & 2) != 0;
    float s1 = hi2 ? mx : my;
    float r1 = __shfl_xor(s1, 2);
    float v = (hi2 ? my : mx) + r1;
    v += __shfl_xor(v, 4);
    v += __shfl_xor(v, 8);
    v += __shfl_xor(v, 16);
    v += __shfl_xor(v, 32);

    if (lane < 4) {
      const float bad = (lane & 1) ? bad_in_f : bad_lb_f;
      const float s = v + kNegInf * bad;
      const int slot = ((lane & 1) << 1) | ((lane >> 1) & 1);  // il0 ii2 ll1 li3
      sims[1 + slot * KK + k] = s;
    }
  }
  __syncthreads();

  const float v = sims[1 + tid];
  const float s0 = sims[0];
  float wmax = waveReduceMax(v);
  if (lane == 0) wred[wave] = wmax;
  __syncthreads();
  float m = fmaxf(fmaxf(wred[0], wred[1]), fmaxf(wred[2], wred[3]));
  m = fmaxf(m, s0);
  const float e = expf(v - m);
  float wsum = waveReduceSum(e);
  if (lane == 0) wred[4 + wave] = wsum;
  __syncthreads();
  if (tid == 0) {
    const float tot = wred[4] + wred[5] + wred[6] + wred[7] + expf(s0 - m);
    per_ex[b] = m + logf(tot) - s0;
    const float max_il = wred[0];  // wave 0 reduced sims[1..64] = il negatives
    if (s0 >= max_il) atomicAdd(&stats[1], 1u);
  }
}

// Exact f32 pass. mode==0: full compute (fallback, counts acc).
// mode==1: fixup — recompute only rows whose bf16 per_ex is near the
// scale-branch threshold; no acc counting.
__global__ __launch_bounds__(256) void row_f32_kernel(
    const float* __restrict__ ie, const float* __restrict__ le,
    const float* __restrict__ labels, const float* __restrict__ ale,
    const float* __restrict__ al, const int* __restrict__ nin,
    const int* __restrict__ nlb, float* __restrict__ per_ex,
    unsigned* __restrict__ stats, int mode) {
  const int b = blockIdx.x;
  if (mode == 1 && per_ex[b] >= 1.5f) return;
  const int tid = threadIdx.x;
  const int lane = tid & 63;
  const int wave = tid >> 6;

  __shared__ float sims[1 + 4 * KK];
  __shared__ float wred[8];

  const float4* ie4 = (const float4*)(ie + (size_t)b * DD);
  const float4* le4 = (const float4*)(le + (size_t)b * DD);
  float4 ier0 = ie4[lane], ier1 = ie4[lane + 64];
  float4 ler0 = le4[lane], ler1 = le4[lane + 64];
  float lab = (lane < LLAB) ? labels[(size_t)b * LLAB + lane] : 0.0f;

  if (wave == 0) {
    float p = dot4(ier0, ler0) + dot4(ier1, ler1);
    p = waveReduceSum(p);
    if (lane == 0) sims[0] = p;
  }

#pragma unroll 2
  for (int kk = 0; kk < KK / 4; ++kk) {
    const int k = wave * (KK / 4) + kk;
    const int j_lb = __builtin_amdgcn_readfirstlane(nlb[(size_t)b * KK + k]);
    const int j_in = __builtin_amdgcn_readfirstlane(nin[(size_t)b * KK + k]);

    const float4* rle = (const float4*)(ale + (size_t)j_lb * DD);
    const float4* rie = (const float4*)(ie + (size_t)j_in * DD);
    float4 vle0 = rle[lane], vle1 = rle[lane + 64];
    float4 vie0 = rie[lane], vie1 = rie[lane + 64];

    bool ein = true, elb = true;
    if (lane < LLAB) {
      ein = (labels[(size_t)j_in * LLAB + lane] == lab);
      elb = (al[(size_t)j_lb * LLAB + lane] == lab);
    }
    const float bad_in_f = (__ballot(ein) == ~0ull) ? 1.0f : 0.0f;
    const float bad_lb_f = (__ballot(elb) == ~0ull) ? 1.0f : 0.0f;

    float a_il = dot4(vle0, ier0) + dot4(vle1, ier1);
    float a_ll = dot4(vle0, ler0) + dot4(vle1, ler1);
    float a_ii = dot4(vie0, ier0) + dot4(vie1, ier1);
    float a_li = dot4(vie0, ler0) + dot4(vie1, ler1);

    const bool oddl = (lane & 1) != 0;
    float sx = oddl ? a_il : a_ii;
    float sy = oddl ? a_ll : a_li;
    float rx = __shfl_xor(sx, 1);
    float ry = __shfl_xor(sy, 1);
    float mx = (oddl ? a_ii : a_il) + rx;
    float my = (oddl ? a_li : a_ll) + ry;
    const bool hi2 = (lane & 2) != 0;
    float s1 = hi2 ? mx : my;
    float r1 = __shfl_xor(s1, 2);
    float v = (hi2 ? my : mx) + r1;
    v += __shfl_xor(v, 4);
    v += __shfl_xor(v, 8);
    v += __shfl_xor(v, 16);
    v += __shfl_xor(v, 32);

    if (lane < 4) {
      const float bad = (lane & 1) ? bad_in_f : bad_lb_f;
      const float s = v + kNegInf * bad;
      const int slot = ((lane & 1) << 1) | ((lane >> 1) & 1);
      sims[1 + slot * KK + k] = s;
    }
  }
  __syncthreads();

  const float v = sims[1 + tid];
  const float s0 = sims[0];
  float wmax = waveReduceMax(v);
  if (lane == 0) wred[wave] = wmax;
  __syncthreads();
  float m = fmaxf(fmaxf(wred[0], wred[1]), fmaxf(wred[2], wred[3]));
  m = fmaxf(m, s0);
  const float e = expf(v - m);
  float wsum = waveReduceSum(e);
  if (lane == 0) wred[4 + wave] = wsum;
  __syncthreads();
  if (tid == 0) {
    const float tot = wred[4] + wred[5] + wred[6] + wred[7] + expf(s0 - m);
    per_ex[b] = m + logf(tot) - s0;
    if (mode == 0) {
      const float max_il = wred[0];
      if (s0 >= max_il) atomicAdd(&stats[1], 1u);
    }
  }
}

__global__ __launch_bounds__(256) void finalize_kernel(
    const float* __restrict__ per_ex, const unsigned* __restrict__ stats,
    float* __restrict__ out) {
  __shared__ float wred[8];
  const int tid = threadIdx.x;
  const int lane = tid & 63;
  const int wave = tid >> 6;

  float mn = 1.0e30f;
  for (int i = tid; i < BB; i += 256) mn = fminf(mn, per_ex[i]);
  mn = waveReduceMin(mn);
  if (lane == 0) wred[wave] = mn;
  __syncthreads();
  const float minpe = fminf(fminf(wred[0], wred[1]), fminf(wred[2], wred[3]));
  const bool scale_on = (minpe < kLn2);  // max(q) > 0.5
  __syncthreads();

  float sum = 0.0f;
  for (int i = tid; i < BB; i += 256) {
    const float pe = per_ex[i];
    float s = 1.0f;
    if (scale_on) {
      const float q = expf(-pe);
      const float t = 2.0f * (1.0f - q);
      const float t2 = t * t;
      s = t2 * t2;
    }
    sum += pe * s;
  }
  sum = waveReduceSum(sum);
  if (lane == 0) wred[4 + wave] = sum;
  __syncthreads();
  if (tid == 0) {
    const float tot = wred[4] + wred[5] + wred[6] + wred[7];
    out[0] = tot / (float)BB;
    out[1] = (float)stats[1] / (float)BB;
  }
}

extern "C" void kernel_launch(void* const* d_in, const int* in_sizes, int n_in,
                              void* d_out, int out_size, void* d_ws, size_t ws_size,
                              hipStream_t stream) {
  const float* ie = (const float*)d_in[0];
  const float* le = (const float*)d_in[1];
  const float* labels = (const float*)d_in[2];
  const float* ale = (const float*)d_in[3];
  const float* al = (const float*)d_in[4];
  const int* nin = (const int*)d_in[5];
  const int* nlb = (const int*)d_in[6];
  float* out = (float*)d_out;

  float* per_ex = (float*)d_ws;
  unsigned* stats = (unsigned*)((char*)d_ws + BB * sizeof(float));

  const size_t off_ie = 16896;  // 16 KB per_ex + stats, 256-aligned
  const size_t off_ale = off_ie + (size_t)BB * DD * 2;
  const size_t need = off_ale + (size_t)NN * DD * 2;

  hipLaunchKernelGGL(init_kernel, dim3(1), dim3(64), 0, stream, stats);

  if (ws_size >= need) {
    ushort* ie_bf = (ushort*)((char*)d_ws + off_ie);
    ushort* ale_bf = (ushort*)((char*)d_ws + off_ale);
    const int n8_ie = BB * DD / 8;
    const int n8_ale = NN * DD / 8;
    hipLaunchKernelGGL(cvt_kernel, dim3(n8_ie / 256), dim3(256), 0, stream, ie, ie_bf, n8_ie);
    hipLaunchKernelGGL(cvt_kernel, dim3(n8_ale / 256), dim3(256), 0, stream, ale, ale_bf, n8_ale);
    hipLaunchKernelGGL(row_bf16_kernel, dim3(BB), dim3(256), 0, stream,
                       ie, le, labels, ie_bf, ale_bf, al, nin, nlb, per_ex, stats);
    hipLaunchKernelGGL(row_f32_kernel, dim3(BB), dim3(256), 0, stream,
                       ie, le, labels, ale, al, nin, nlb, per_ex, stats, 1);
  } else {
    hipLaunchKernelGGL(row_f32_kernel, dim3(BB), dim3(256), 0, stream,
                       ie, le, labels, ale, al, nin, nlb, per_ex, stats, 0);
  }
  hipLaunchKernelGGL(finalize_kernel, dim3(1), dim3(256), 0, stream,
                     per_ex, stats, out);
}

// Round 3
// 92.573 us; speedup vs baseline: 1.6665x; 1.1957x over previous
//
#include <hip/hip_runtime.h>
#include <hip/hip_bf16.h>

#define BB 4096
#define DD 512
#define LLAB 20
#define NN 8192
#define KK 64

constexpr float kNegInf = -1.0e9f;
constexpr float kLn2 = 0.69314718055994530942f;

// workspace layout (bytes)
#define OFF_STATS 16384
#define OFF_WL    16640
#define OFF_HLAB  33280
#define OFF_HAL   66048
#define OFF_IEBF  131584
#define OFF_ALEBF (OFF_IEBF + (size_t)BB * DD * 2)
#define WS_NEED   (OFF_ALEBF + (size_t)NN * DD * 2)

__device__ __forceinline__ float dot4(const float4& a, const float4& b) {
  return a.x * b.x + a.y * b.y + a.z * b.z + a.w * b.w;
}

__device__ __forceinline__ float waveReduceSum(float v) {
#pragma unroll
  for (int s = 1; s < 64; s <<= 1) v += __shfl_xor(v, s);
  return v;
}

__device__ __forceinline__ float waveReduceMax(float v) {
#pragma unroll
  for (int s = 1; s < 64; s <<= 1) v = fmaxf(v, __shfl_xor(v, s));
  return v;
}

__device__ __forceinline__ float waveReduceMin(float v) {
#pragma unroll
  for (int s = 1; s < 64; s <<= 1) v = fminf(v, __shfl_xor(v, s));
  return v;
}

__device__ __forceinline__ unsigned f2bf_rne(float x) {
  unsigned u = __float_as_uint(x);
  u += 0x7fffu + ((u >> 16) & 1u);
  return u >> 16;
}

__device__ __forceinline__ void cvt8(const float* __restrict__ src,
                                     ushort* __restrict__ dst, int i) {
  const float4* s4 = (const float4*)src;
  float4 a = s4[2 * i], c = s4[2 * i + 1];
  uint4 o;
  o.x = f2bf_rne(a.x) | (f2bf_rne(a.y) << 16);
  o.y = f2bf_rne(a.z) | (f2bf_rne(a.w) << 16);
  o.z = f2bf_rne(c.x) | (f2bf_rne(c.y) << 16);
  o.w = f2bf_rne(c.z) | (f2bf_rne(c.w) << 16);
  ((uint4*)dst)[i] = o;
}

__device__ __forceinline__ unsigned long long hash20(const float* __restrict__ p) {
  unsigned long long h = 1469598103934665603ull;
#pragma unroll
  for (int t = 0; t < LLAB; ++t) {
    h ^= (unsigned long long)__float_as_uint(p[t]);
    h *= 1099511628211ull;
  }
  return h;
}

__device__ __forceinline__ void unpack8(const uint4& p, float* f) {
  f[0] = __uint_as_float(p.x << 16);
  f[1] = __uint_as_float(p.x & 0xffff0000u);
  f[2] = __uint_as_float(p.y << 16);
  f[3] = __uint_as_float(p.y & 0xffff0000u);
  f[4] = __uint_as_float(p.z << 16);
  f[5] = __uint_as_float(p.z & 0xffff0000u);
  f[6] = __uint_as_float(p.w << 16);
  f[7] = __uint_as_float(p.w & 0xffff0000u);
}

__device__ __forceinline__ float dot8(const float* f, const float4& q0, const float4& q1) {
  return f[0] * q0.x + f[1] * q0.y + f[2] * q0.z + f[3] * q0.w +
         f[4] * q1.x + f[5] * q1.y + f[6] * q1.z + f[7] * q1.w;
}

__global__ void init_kernel(unsigned* stats) {
  if (threadIdx.x == 0) {
    stats[0] = 0u;  // acc count
    stats[1] = 0u;  // worklist count
  }
}

// Fused prep: bf16-convert both tables, hash both label tables, init stats.
__global__ __launch_bounds__(256) void prep_kernel(
    const float* __restrict__ ie, const float* __restrict__ ale,
    const float* __restrict__ labels, const float* __restrict__ al,
    ushort* __restrict__ ie_bf, ushort* __restrict__ ale_bf,
    unsigned long long* __restrict__ h_lab, unsigned long long* __restrict__ h_al,
    unsigned* __restrict__ stats) {
  const int i = blockIdx.x * 256 + threadIdx.x;
  if (i == 0) {
    stats[0] = 0u;
    stats[1] = 0u;
  }
  const int n8_ie = BB * DD / 8;
  if (i < n8_ie) {
    cvt8(ie, ie_bf, i);
  } else {
    cvt8(ale, ale_bf, i - n8_ie);
  }
  if (i < BB) {
    h_lab[i] = hash20(labels + (size_t)i * LLAB);
  } else if (i < BB + NN) {
    h_al[i - BB] = hash20(al + (size_t)(i - BB) * LLAB);
  }
}

// Main pass: one block (4 waves) per row; each wave owns 16 negatives.
__global__ __launch_bounds__(256, 8) void row_bf16_kernel(
    const float* __restrict__ ie, const float* __restrict__ le,
    const ushort* __restrict__ ie_bf, const ushort* __restrict__ ale_bf,
    const unsigned long long* __restrict__ h_lab,
    const unsigned long long* __restrict__ h_al,
    const int* __restrict__ nin, const int* __restrict__ nlb,
    float* __restrict__ per_ex, int* __restrict__ wl,
    unsigned* __restrict__ stats) {
  const int b = blockIdx.x;
  const int tid = threadIdx.x;
  const int lane = tid & 63;
  const int wave = tid >> 6;

  __shared__ float sims[1 + 4 * KK];
  __shared__ float wred[8];

  // Query fragments (exact f32): elements lane*8 .. lane*8+7.
  const float4* ie4 = (const float4*)(ie + (size_t)b * DD);
  const float4* le4 = (const float4*)(le + (size_t)b * DD);
  float4 qi0 = ie4[2 * lane], qi1 = ie4[2 * lane + 1];
  float4 ql0 = le4[2 * lane], ql1 = le4[2 * lane + 1];

  if (wave == 0) {
    float p = dot4(qi0, ql0) + dot4(qi1, ql1);
    p = waveReduceSum(p);
    if (lane == 0) sims[0] = p;
  }

  const unsigned long long hb = h_lab[b];
  const int wuni = __builtin_amdgcn_readfirstlane(wave);
  const int base = b * KK + wuni * 16;

#pragma unroll 8
  for (int kk = 0; kk < 16; ++kk) {
    const int k = wuni * 16 + kk;
    const int j_lb = nlb[base + kk];  // uniform -> s_load
    const int j_in = nin[base + kk];  // uniform -> s_load

    const uint4 ple = ((const uint4*)(ale_bf + (size_t)j_lb * DD))[lane];
    const uint4 pie = ((const uint4*)(ie_bf + (size_t)j_in * DD))[lane];

    const bool bad_lb = (h_al[j_lb] == hb);   // scalar load + compare
    const bool bad_in = (h_lab[j_in] == hb);  // scalar load + compare

    float fle[8], fie[8];
    unpack8(ple, fle);
    unpack8(pie, fie);
    float a_il = dot8(fle, qi0, qi1);
    float a_ll = dot8(fle, ql0, ql1);
    float a_ii = dot8(fie, qi0, qi1);
    float a_li = dot8(fie, ql0, ql1);

    // component-split butterfly; lane&3: 0->il, 1->ii, 2->ll, 3->li
    const bool oddl = (lane & 1) != 0;
    float sx = oddl ? a_il : a_ii;
    float sy = oddl ? a_ll : a_li;
    float rx = __shfl_xor(sx, 1);
    float ry = __shfl_xor(sy, 1);
    float mx = (oddl ? a_ii : a_il) + rx;
    float my = (oddl ? a_li : a_ll) + ry;
    const bool hi2 = (lane & 2) != 0;
    float s1 = hi2 ? mx : my;
    float r1 = __shfl_xor(s1, 2);
    float v = (hi2 ? my : mx) + r1;
    v += __shfl_xor(v, 4);
    v += __shfl_xor(v, 8);
    v += __shfl_xor(v, 16);
    v += __shfl_xor(v, 32);

    if (lane < 4) {
      const bool badf = (lane & 1) ? bad_in : bad_lb;
      const float s = badf ? v + kNegInf : v;
      const int slot = ((lane & 1) << 1) | ((lane >> 1) & 1);  // il0 ii2 ll1 li3
      sims[1 + slot * KK + k] = s;
    }
  }
  __syncthreads();

  const float v = sims[1 + tid];
  const float s0 = sims[0];
  float wmax = waveReduceMax(v);
  if (lane == 0) wred[wave] = wmax;
  __syncthreads();
  float m = fmaxf(fmaxf(wred[0], wred[1]), fmaxf(wred[2], wred[3]));
  m = fmaxf(m, s0);
  const float e = expf(v - m);
  float wsum = waveReduceSum(e);
  if (lane == 0) wred[4 + wave] = wsum;
  __syncthreads();
  if (tid == 0) {
    const float tot = wred[4] + wred[5] + wred[6] + wred[7] + expf(s0 - m);
    const float pe = m + logf(tot) - s0;
    per_ex[b] = pe;
    if (pe < 1.5f) {  // near the scale-branch threshold: exact recompute later
      const unsigned p = atomicAdd(&stats[1], 1u);
      wl[p] = b;
    }
    const float max_il = wred[0];  // wave 0 reduced sims[1..64] = il negatives
    if (s0 >= max_il) atomicAdd(&stats[0], 1u);
  }
}

// Exact f32 row compute (shared by fallback and fixup).
__device__ __forceinline__ void row_f32_body(
    int b, const float* __restrict__ ie, const float* __restrict__ le,
    const float* __restrict__ labels, const float* __restrict__ ale,
    const float* __restrict__ al, const int* __restrict__ nin,
    const int* __restrict__ nlb, float* __restrict__ per_ex,
    unsigned* __restrict__ stats, bool count_acc, float* sims, float* wred) {
  const int tid = threadIdx.x;
  const int lane = tid & 63;
  const int wave = tid >> 6;

  const float4* ie4 = (const float4*)(ie + (size_t)b * DD);
  const float4* le4 = (const float4*)(le + (size_t)b * DD);
  float4 ier0 = ie4[lane], ier1 = ie4[lane + 64];
  float4 ler0 = le4[lane], ler1 = le4[lane + 64];
  float lab = (lane < LLAB) ? labels[(size_t)b * LLAB + lane] : 0.0f;

  if (wave == 0) {
    float p = dot4(ier0, ler0) + dot4(ier1, ler1);
    p = waveReduceSum(p);
    if (lane == 0) sims[0] = p;
  }

#pragma unroll 2
  for (int kk = 0; kk < KK / 4; ++kk) {
    const int k = wave * (KK / 4) + kk;
    const int j_lb = __builtin_amdgcn_readfirstlane(nlb[(size_t)b * KK + k]);
    const int j_in = __builtin_amdgcn_readfirstlane(nin[(size_t)b * KK + k]);

    const float4* rle = (const float4*)(ale + (size_t)j_lb * DD);
    const float4* rie = (const float4*)(ie + (size_t)j_in * DD);
    float4 vle0 = rle[lane], vle1 = rle[lane + 64];
    float4 vie0 = rie[lane], vie1 = rie[lane + 64];

    bool ein = true, elb = true;
    if (lane < LLAB) {
      ein = (labels[(size_t)j_in * LLAB + lane] == lab);
      elb = (al[(size_t)j_lb * LLAB + lane] == lab);
    }
    const bool bad_in = (__ballot(ein) == ~0ull);
    const bool bad_lb = (__ballot(elb) == ~0ull);

    float a_il = dot4(vle0, ier0) + dot4(vle1, ier1);
    float a_ll = dot4(vle0, ler0) + dot4(vle1, ler1);
    float a_ii = dot4(vie0, ier0) + dot4(vie1, ier1);
    float a_li = dot4(vie0, ler0) + dot4(vie1, ler1);

    const bool oddl = (lane & 1) != 0;
    float sx = oddl ? a_il : a_ii;
    float sy = oddl ? a_ll : a_li;
    float rx = __shfl_xor(sx, 1);
    float ry = __shfl_xor(sy, 1);
    float mx = (oddl ? a_ii : a_il) + rx;
    float my = (oddl ? a_li : a_ll) + ry;
    const bool hi2 = (lane & 2) != 0;
    float s1 = hi2 ? mx : my;
    float r1 = __shfl_xor(s1, 2);
    float v = (hi2 ? my : mx) + r1;
    v += __shfl_xor(v, 4);
    v += __shfl_xor(v, 8);
    v += __shfl_xor(v, 16);
    v += __shfl_xor(v, 32);

    if (lane < 4) {
      const bool badf = (lane & 1) ? bad_in : bad_lb;
      const float s = badf ? v + kNegInf : v;
      const int slot = ((lane & 1) << 1) | ((lane >> 1) & 1);
      sims[1 + slot * KK + k] = s;
    }
  }
  __syncthreads();

  const float v = sims[1 + tid];
  const float s0 = sims[0];
  float wmax = waveReduceMax(v);
  if (lane == 0) wred[wave] = wmax;
  __syncthreads();
  float m = fmaxf(fmaxf(wred[0], wred[1]), fmaxf(wred[2], wred[3]));
  m = fmaxf(m, s0);
  const float e = expf(v - m);
  float wsum = waveReduceSum(e);
  if (lane == 0) wred[4 + wave] = wsum;
  __syncthreads();
  if (tid == 0) {
    const float tot = wred[4] + wred[5] + wred[6] + wred[7] + expf(s0 - m);
    per_ex[b] = m + logf(tot) - s0;
    if (count_acc) {
      const float max_il = wred[0];
      if (s0 >= max_il) atomicAdd(&stats[0], 1u);
    }
  }
}

// Fallback: full exact pass (used only if ws too small).
__global__ __launch_bounds__(256) void row_f32_kernel(
    const float* __restrict__ ie, const float* __restrict__ le,
    const float* __restrict__ labels, const float* __restrict__ ale,
    const float* __restrict__ al, const int* __restrict__ nin,
    const int* __restrict__ nlb, float* __restrict__ per_ex,
    unsigned* __restrict__ stats) {
  __shared__ float sims[1 + 4 * KK];
  __shared__ float wred[8];
  row_f32_body(blockIdx.x, ie, le, labels, ale, al, nin, nlb, per_ex, stats,
               true, sims, wred);
}

// Fixup: exact recompute of worklist rows (scale-branch safety).
__global__ __launch_bounds__(256) void fixup_kernel(
    const float* __restrict__ ie, const float* __restrict__ le,
    const float* __restrict__ labels, const float* __restrict__ ale,
    const float* __restrict__ al, const int* __restrict__ nin,
    const int* __restrict__ nlb, float* __restrict__ per_ex,
    const int* __restrict__ wl, const unsigned* __restrict__ stats) {
  __shared__ float sims[1 + 4 * KK];
  __shared__ float wred[8];
  const int n = (int)stats[1];
  for (int w = blockIdx.x; w < n; w += gridDim.x) {
    row_f32_body(wl[w], ie, le, labels, ale, al, nin, nlb, per_ex,
                 (unsigned*)nullptr, false, sims, wred);
    __syncthreads();
  }
}

__global__ __launch_bounds__(256) void finalize_kernel(
    const float* __restrict__ per_ex, const unsigned* __restrict__ stats,
    float* __restrict__ out) {
  __shared__ float wred[8];
  const int tid = threadIdx.x;
  const int lane = tid & 63;
  const int wave = tid >> 6;

  float mn = 1.0e30f;
  for (int i = tid; i < BB; i += 256) mn = fminf(mn, per_ex[i]);
  mn = waveReduceMin(mn);
  if (lane == 0) wred[wave] = mn;
  __syncthreads();
  const float minpe = fminf(fminf(wred[0], wred[1]), fminf(wred[2], wred[3]));
  const bool scale_on = (minpe < kLn2);  // max(q) > 0.5
  __syncthreads();

  float sum = 0.0f;
  for (int i = tid; i < BB; i += 256) {
    const float pe = per_ex[i];
    float s = 1.0f;
    if (scale_on) {
      const float q = expf(-pe);
      const float t = 2.0f * (1.0f - q);
      const float t2 = t * t;
      s = t2 * t2;
    }
    sum += pe * s;
  }
  sum = waveReduceSum(sum);
  if (lane == 0) wred[4 + wave] = sum;
  __syncthreads();
  if (tid == 0) {
    const float tot = wred[4] + wred[5] + wred[6] + wred[7];
    out[0] = tot / (float)BB;
    out[1] = (float)stats[0] / (float)BB;
  }
}

extern "C" void kernel_launch(void* const* d_in, const int* in_sizes, int n_in,
                              void* d_out, int out_size, void* d_ws, size_t ws_size,
                              hipStream_t stream) {
  const float* ie = (const float*)d_in[0];
  const float* le = (const float*)d_in[1];
  const float* labels = (const float*)d_in[2];
  const float* ale = (const float*)d_in[3];
  const float* al = (const float*)d_in[4];
  const int* nin = (const int*)d_in[5];
  const int* nlb = (const int*)d_in[6];
  float* out = (float*)d_out;

  float* per_ex = (float*)d_ws;
  unsigned* stats = (unsigned*)((char*)d_ws + OFF_STATS);
  int* wl = (int*)((char*)d_ws + OFF_WL);

  if (ws_size >= WS_NEED) {
    ushort* ie_bf = (ushort*)((char*)d_ws + OFF_IEBF);
    ushort* ale_bf = (ushort*)((char*)d_ws + OFF_ALEBF);
    unsigned long long* h_lab = (unsigned long long*)((char*)d_ws + OFF_HLAB);
    unsigned long long* h_al = (unsigned long long*)((char*)d_ws + OFF_HAL);
    const int prep_blocks = (BB * DD / 8 + NN * DD / 8) / 256;
    hipLaunchKernelGGL(prep_kernel, dim3(prep_blocks), dim3(256), 0, stream,
                       ie, ale, labels, al, ie_bf, ale_bf, h_lab, h_al, stats);
    hipLaunchKernelGGL(row_bf16_kernel, dim3(BB), dim3(256), 0, stream,
                       ie, le, ie_bf, ale_bf, h_lab, h_al, nin, nlb, per_ex, wl, stats);
    hipLaunchKernelGGL(fixup_kernel, dim3(128), dim3(256), 0, stream,
                       ie, le, labels, ale, al, nin, nlb, per_ex, wl, stats);
  } else {
    hipLaunchKernelGGL(init_kernel, dim3(1), dim3(64), 0, stream, stats);
    hipLaunchKernelGGL(row_f32_kernel, dim3(BB), dim3(256), 0, stream,
                       ie, le, labels, ale, al, nin, nlb, per_ex, stats);
  }
  hipLaunchKernelGGL(finalize_kernel, dim3(1), dim3(256), 0, stream,
                     per_ex, stats, out);
}